// Round 1
// baseline (254.013 us; speedup 1.0000x reference)
//
#include <hip/hip_runtime.h>

// GraphProjection: out[N,963] = concat(verts[N,3], proj(f0)[N,64], proj(f1)[N,128],
//                                      proj(f2)[N,256], proj(f3)[N,512])
// Degenerate "bilinear": weights collapse to w11 = (x2-x1)*(y2-y1) in {0,1};
// every feature element is a masked gather of feat[c, floor(x), floor(y)].
//
// V2: main kernel is a flat float4-per-thread writer (aligned dwordx4 nontemporal
// stores over the contiguous out buffer), magic-div by 963 for (row,col) decode.
// prep_params fused into the transpose kernel (2 dispatches total on the fast path).

static constexpr int NV      = 50000;
static constexpr int TOTAL   = 963 * NV;          // 48,150,000 (divisible by 4)
static constexpr int B_VERTS = 3 * NV;            // 150,000
static constexpr int B_F0    = B_VERTS + 64 * NV; // 3,350,000
static constexpr int B_F1    = B_F0 + 128 * NV;   // 9,750,000
static constexpr int B_F2    = B_F1 + 256 * NV;   // 22,550,000

// transposed feature sizes (floats): [S*S, C]
static constexpr int T0 = 56 * 56 * 64;   // 200,704
static constexpr int T1 = 28 * 28 * 128;  // 100,352
static constexpr int T2 = 14 * 14 * 256;  // 50,176
static constexpr int T3 = 7 * 7 * 512;    // 25,088
static constexpr int TSUM = T0 + T1 + T2 + T3; // 376,320

typedef float f32x4 __attribute__((ext_vector_type(4)));

// n = idx / 963 for 0 <= idx < 48,150,000.
// M = ceil(2^41 / 963) = 2,283,513,246; M*963 - 2^41 = 346.
// max error = 48.15e6 * (346/963) / 2^41 ~= 7.9e-6 < 1/963  -> exact floor div.
__device__ __forceinline__ int div963(int x) {
  return (int)(((unsigned long long)(unsigned)x * 2283513246ull) >> 41);
}

__device__ __forceinline__ void proj_hw(const float* __restrict__ verts, int n,
                                        float& h, float& w) {
  float v0 = verts[3 * n + 0];
  float v1 = verts[3 * n + 1];
  float v2 = verts[3 * n + 2];
  // match numpy fp32 exactly: no FMA contraction, IEEE rn division
  h = __fadd_rn(__fmul_rn(248.0f, __fdiv_rn(v1, v2)), 111.5f);
  w = __fadd_rn(__fmul_rn(248.0f, __fdiv_rn(v0, -v2)), 111.5f);
  h = fminf(fmaxf(h, 0.0f), 223.0f);
  w = fminf(fmaxf(w, 0.0f), 223.0f);
}

__device__ __forceinline__ int level_off(float h, float w, float scale, int S) {
  float x = h * scale;  // scale = S/224 is an exact power of two
  float y = w * scale;
  int x1 = (int)floorf(x);
  int x2 = min((int)ceilf(x), S - 1);
  int y1 = (int)floorf(y);
  int y2 = min((int)ceilf(y), S - 1);
  return (x2 > x1 && y2 > y1) ? (x1 * S + y1) : -1;
}

// Fused: first NV threads compute per-vertex params; remaining TSUM threads
// transpose [C,S,S] -> [S*S,C] so per-vertex channel gathers are contiguous.
__global__ __launch_bounds__(256) void prep_all_k(
    const float* __restrict__ verts,
    const float* __restrict__ f0, const float* __restrict__ f1,
    const float* __restrict__ f2, const float* __restrict__ f3,
    int* __restrict__ params,
    float* __restrict__ t0, float* __restrict__ t1,
    float* __restrict__ t2, float* __restrict__ t3) {
  int i = blockIdx.x * 256 + threadIdx.x;
  if (i < NV) {
    float h, w;
    proj_hw(verts, i, h, w);
    params[4 * i + 0] = level_off(h, w, 0.25f,    56);
    params[4 * i + 1] = level_off(h, w, 0.125f,   28);
    params[4 * i + 2] = level_off(h, w, 0.0625f,  14);
    params[4 * i + 3] = level_off(h, w, 0.03125f, 7);
    return;
  }
  int j = i - NV;
  if (j < T0) { int off = j >> 6, c = j & 63;  t0[j] = f0[c * 3136 + off]; return; }
  j -= T0;
  if (j < T1) { int off = j >> 7, c = j & 127; t1[j] = f1[c * 784 + off];  return; }
  j -= T1;
  if (j < T2) { int off = j >> 8, c = j & 255; t2[j] = f2[c * 196 + off];  return; }
  j -= T2;
  if (j < T3) { int off = j >> 9, c = j & 511; t3[j] = f3[c * 49 + off];   return; }
}

__device__ __forceinline__ float fetch_elem(
    int ne, int ce,
    const float* __restrict__ verts,
    const float* __restrict__ t0, const float* __restrict__ t1,
    const float* __restrict__ t2, const float* __restrict__ t3,
    const int* __restrict__ params) {
  if (ce < 3) return verts[3 * ne + ce];
  if (ce < 67) {
    int off = params[4 * ne + 0];
    return (off >= 0) ? t0[(off << 6) + (ce - 3)] : 0.0f;
  }
  if (ce < 195) {
    int off = params[4 * ne + 1];
    return (off >= 0) ? t1[(off << 7) + (ce - 67)] : 0.0f;
  }
  if (ce < 451) {
    int off = params[4 * ne + 2];
    return (off >= 0) ? t2[(off << 8) + (ce - 195)] : 0.0f;
  }
  int off = params[4 * ne + 3];
  return (off >= 0) ? t3[(off << 9) + (ce - 451)] : 0.0f;
}

// Flat float4 writer: thread t owns out dwords [4t, 4t+4). Aligned 16B
// nontemporal stores, fully coalesced; reads hit L2-hot transposed feats.
__global__ __launch_bounds__(256) void gp_vec_k(
    const float* __restrict__ verts,
    const float* __restrict__ t0, const float* __restrict__ t1,
    const float* __restrict__ t2, const float* __restrict__ t3,
    const int* __restrict__ params, float* __restrict__ out) {
  int tid = blockIdx.x * 256 + threadIdx.x;
  int i4 = tid * 4;
  if (i4 >= TOTAL) return;

  int n = div963(i4);
  int col = i4 - n * 963;  // 0..962

  // element 0
  float v0 = fetch_elem(n, col, verts, t0, t1, t2, t3, params);
  // elements 1..3: at most one row crossing within 4 consecutive dwords
  int n1 = n, c1 = col + 1; if (c1 >= 963) { c1 -= 963; ++n1; }
  float v1 = fetch_elem(n1, c1, verts, t0, t1, t2, t3, params);
  int n2 = n, c2 = col + 2; if (c2 >= 963) { c2 -= 963; ++n2; }
  float v2 = fetch_elem(n2, c2, verts, t0, t1, t2, t3, params);
  int n3 = n, c3 = col + 3; if (c3 >= 963) { c3 -= 963; ++n3; }
  float v3 = fetch_elem(n3, c3, verts, t0, t1, t2, t3, params);

  f32x4 r;
  r.x = v0; r.y = v1; r.z = v2; r.w = v3;
  __builtin_nontemporal_store(r, reinterpret_cast<f32x4*>(out + i4));
}

// ---------- fallback paths (small workspace) ----------
// MODE 1: original feats + params; MODE 2: original feats, params inline
template <int MODE>
__device__ __forceinline__ int get_off(const int* __restrict__ params,
                                       const float* __restrict__ verts,
                                       int n, int k, float scale, int S) {
  if (MODE < 2) return params[4 * n + k];
  float h, w;
  proj_hw(verts, n, h, w);
  return level_off(h, w, scale, S);
}

__global__ __launch_bounds__(256) void prep_params_k(const float* __restrict__ verts,
                                                     int* __restrict__ params) {
  int n = blockIdx.x * 256 + threadIdx.x;
  if (n >= NV) return;
  float h, w;
  proj_hw(verts, n, h, w);
  params[4 * n + 0] = level_off(h, w, 0.25f,    56);
  params[4 * n + 1] = level_off(h, w, 0.125f,   28);
  params[4 * n + 2] = level_off(h, w, 0.0625f,  14);
  params[4 * n + 3] = level_off(h, w, 0.03125f, 7);
}

template <int MODE>
__global__ __launch_bounds__(256) void gp_main_k(
    const float* __restrict__ verts,
    const float* __restrict__ f0, const float* __restrict__ f1,
    const float* __restrict__ f2, const float* __restrict__ f3,
    const int* __restrict__ params, float* __restrict__ out) {
  int j = blockIdx.x * 256 + threadIdx.x;
  if (j >= TOTAL) return;

  if (j < B_VERTS) {
    int n = j / 3;
    int col = j - 3 * n;
    out[n * 963 + col] = verts[j];
    return;
  }

  int n, outcol;
  float val = 0.0f;
  if (j < B_F0) {
    int t = j - B_VERTS; n = t >> 6; int c = t & 63;
    int off = get_off<MODE>(params, verts, n, 0, 0.25f, 56);
    if (off >= 0) val = f0[c * 3136 + off];
    outcol = 3 + c;
  } else if (j < B_F1) {
    int t = j - B_F0; n = t >> 7; int c = t & 127;
    int off = get_off<MODE>(params, verts, n, 1, 0.125f, 28);
    if (off >= 0) val = f1[c * 784 + off];
    outcol = 67 + c;
  } else if (j < B_F2) {
    int t = j - B_F1; n = t >> 8; int c = t & 255;
    int off = get_off<MODE>(params, verts, n, 2, 0.0625f, 14);
    if (off >= 0) val = f2[c * 196 + off];
    outcol = 195 + c;
  } else {
    int t = j - B_F2; n = t >> 9; int c = t & 511;
    int off = get_off<MODE>(params, verts, n, 3, 0.03125f, 7);
    if (off >= 0) val = f3[c * 49 + off];
    outcol = 451 + c;
  }
  out[n * 963 + outcol] = val;
}

extern "C" void kernel_launch(void* const* d_in, const int* in_sizes, int n_in,
                              void* d_out, int out_size, void* d_ws, size_t ws_size,
                              hipStream_t stream) {
  const float* f0    = (const float*)d_in[0];
  const float* f1    = (const float*)d_in[1];
  const float* f2    = (const float*)d_in[2];
  const float* f3    = (const float*)d_in[3];
  const float* verts = (const float*)d_in[4];
  float* out = (float*)d_out;

  const size_t PARAM_BYTES = (size_t)NV * 4 * sizeof(int);               // 800,000 (16B-aligned)
  const size_t FULL_BYTES  = PARAM_BYTES + (size_t)TSUM * sizeof(float); // 2,305,280

  if (ws_size >= FULL_BYTES) {
    int*   params = (int*)d_ws;
    float* t0 = (float*)((char*)d_ws + PARAM_BYTES);
    float* t1 = t0 + T0;
    float* t2 = t1 + T1;
    float* t3 = t2 + T2;
    const int prepBlocks = (NV + TSUM + 255) / 256;
    prep_all_k<<<prepBlocks, 256, 0, stream>>>(verts, f0, f1, f2, f3,
                                               params, t0, t1, t2, t3);
    const int vecBlocks = (TOTAL / 4 + 255) / 256;  // 47,022
    gp_vec_k<<<vecBlocks, 256, 0, stream>>>(verts, t0, t1, t2, t3, params, out);
  } else if (ws_size >= PARAM_BYTES) {
    int* params = (int*)d_ws;
    prep_params_k<<<(NV + 255) / 256, 256, 0, stream>>>(verts, params);
    gp_main_k<1><<<(TOTAL + 255) / 256, 256, 0, stream>>>(verts, f0, f1, f2, f3, params, out);
  } else {
    gp_main_k<2><<<(TOTAL + 255) / 256, 256, 0, stream>>>(verts, f0, f1, f2, f3, nullptr, out);
  }
}

// Round 2
// 203.083 us; speedup vs baseline: 1.2508x; 1.2508x over previous
//
#include <hip/hip_runtime.h>

// GraphProjection: out[N,963] = concat(verts[N,3], proj(f0)[N,64], proj(f1)[N,128],
//                                      proj(f2)[N,256], proj(f3)[N,512])
// Degenerate "bilinear": weights collapse to w11 = (x2-x1)*(y2-y1) in {0,1};
// every feature element is a masked gather of feat[c, floor(x), floor(y)].
//
// V3: wave-per-vertex row copy. All 64 lanes share one vertex n:
//  - params loaded once per wave (int4), readfirstlane -> SGPR bases
//  - 963-dword row copied in 15 unrolled lane-dense iterations + 3-lane tail
//  - 11/15 iterations have compile-time-constant region (branchless);
//    offsets < 0 redirect to a zero block (no per-element select)
// Prep reverted to two small kernels (fused version cost ~10us in round 1).

static constexpr int NV      = 50000;
static constexpr int TOTAL   = 963 * NV;          // 48,150,000

// transposed feature sizes (floats): [S*S, C]
static constexpr int T0 = 56 * 56 * 64;   // 200,704
static constexpr int T1 = 28 * 28 * 128;  // 100,352
static constexpr int T2 = 14 * 14 * 256;  // 50,176
static constexpr int T3 = 7 * 7 * 512;    // 25,088
static constexpr int TSUM = T0 + T1 + T2 + T3; // 376,320
static constexpr int ZN   = 516;          // zero block (covers col-448 up to 514)

__device__ __forceinline__ void proj_hw(const float* __restrict__ verts, int n,
                                        float& h, float& w) {
  float v0 = verts[3 * n + 0];
  float v1 = verts[3 * n + 1];
  float v2 = verts[3 * n + 2];
  // match numpy fp32 exactly: no FMA contraction, IEEE rn division
  h = __fadd_rn(__fmul_rn(248.0f, __fdiv_rn(v1, v2)), 111.5f);
  w = __fadd_rn(__fmul_rn(248.0f, __fdiv_rn(v0, -v2)), 111.5f);
  h = fminf(fmaxf(h, 0.0f), 223.0f);
  w = fminf(fmaxf(w, 0.0f), 223.0f);
}

__device__ __forceinline__ int level_off(float h, float w, float scale, int S) {
  float x = h * scale;  // scale = S/224 is an exact power of two
  float y = w * scale;
  int x1 = (int)floorf(x);
  int x2 = min((int)ceilf(x), S - 1);
  int y1 = (int)floorf(y);
  int y2 = min((int)ceilf(y), S - 1);
  return (x2 > x1 && y2 > y1) ? (x1 * S + y1) : -1;
}

__global__ __launch_bounds__(256) void prep_params_k(const float* __restrict__ verts,
                                                     int* __restrict__ params) {
  int n = blockIdx.x * 256 + threadIdx.x;
  if (n >= NV) return;
  float h, w;
  proj_hw(verts, n, h, w);
  params[4 * n + 0] = level_off(h, w, 0.25f,    56);
  params[4 * n + 1] = level_off(h, w, 0.125f,   28);
  params[4 * n + 2] = level_off(h, w, 0.0625f,  14);
  params[4 * n + 3] = level_off(h, w, 0.03125f, 7);
}

// [C,S,S] -> [S*S, C] so per-wave channel reads are contiguous; also zero-fills
// the ZN-float zero block used for out-of-image vertices.
__global__ __launch_bounds__(256) void transpose_k(
    const float* __restrict__ f0, const float* __restrict__ f1,
    const float* __restrict__ f2, const float* __restrict__ f3,
    float* __restrict__ t0, float* __restrict__ t1,
    float* __restrict__ t2, float* __restrict__ t3,
    float* __restrict__ zeros) {
  int i = blockIdx.x * 256 + threadIdx.x;
  if (i < T0) { int off = i >> 6, c = i & 63;  t0[i] = f0[c * 3136 + off]; return; }
  i -= T0;
  if (i < T1) { int off = i >> 7, c = i & 127; t1[i] = f1[c * 784 + off];  return; }
  i -= T1;
  if (i < T2) { int off = i >> 8, c = i & 255; t2[i] = f2[c * 196 + off];  return; }
  i -= T2;
  if (i < T3) { int off = i >> 9, c = i & 511; t3[i] = f3[c * 49 + off];   return; }
  i -= T3;
  if (i < ZN) zeros[i] = 0.0f;
}

// Wave-per-vertex: 64 lanes copy one 963-dword output row.
// Region bases are wave-uniform (SGPR); cols [0,3)=verts, [3,67)=t0,
// [67,195)=t1, [195,451)=t2, [451,963)=t3.
__global__ __launch_bounds__(256) void gp_row_k(
    const float* __restrict__ verts,
    const float* __restrict__ t0, const float* __restrict__ t1,
    const float* __restrict__ t2, const float* __restrict__ t3,
    const float* __restrict__ zeros,
    const int* __restrict__ params, float* __restrict__ out) {
  int wid  = (blockIdx.x * 256 + threadIdx.x) >> 6;
  int lane = threadIdx.x & 63;
  if (wid >= NV) return;
  const int n = wid;

  // wave-uniform params: one 16B broadcast load, then force into SGPRs
  int4 pv = *reinterpret_cast<const int4*>(params + 4 * n);
  int p0 = __builtin_amdgcn_readfirstlane(pv.x);
  int p1 = __builtin_amdgcn_readfirstlane(pv.y);
  int p2 = __builtin_amdgcn_readfirstlane(pv.z);
  int p3 = __builtin_amdgcn_readfirstlane(pv.w);

  // s_r[col] is valid for col in region r; p<0 redirects into the zero block
  const float* vb = verts + 3 * n;                                  // col in [0,3)
  const float* s0 = ((p0 >= 0) ? t0 + (p0 << 6) : zeros + 3) - 3;   // [3,67)
  const float* s1 = ((p1 >= 0) ? t1 + (p1 << 7) : zeros + 3) - 67;  // [67,195)
  const float* s2 = ((p2 >= 0) ? t2 + (p2 << 8) : zeros + 3) - 195; // [195,451)
  const float* s3 = ((p3 >= 0) ? t3 + (p3 << 9) : zeros + 3) - 451; // [451,963)

  float* o = out + 963 * n;

#pragma unroll
  for (int k = 0; k < 15; ++k) {
    int col = (k << 6) + lane;
    // with k unrolled, 11/15 iterations fold to a single region at compile time
    const float* b = (col < 3)   ? vb
                   : (col < 67)  ? s0
                   : (col < 195) ? s1
                   : (col < 451) ? s2
                   :               s3;
    o[col] = b[col];
  }
  if (lane < 3) {
    int col = 960 + lane;
    o[col] = s3[col];
  }
}

// ---------- fallback paths (small workspace) ----------
template <int MODE>
__device__ __forceinline__ int get_off(const int* __restrict__ params,
                                       const float* __restrict__ verts,
                                       int n, int k, float scale, int S) {
  if (MODE < 2) return params[4 * n + k];
  float h, w;
  proj_hw(verts, n, h, w);
  return level_off(h, w, scale, S);
}

static constexpr int B_VERTS = 3 * NV;            // 150,000
static constexpr int B_F0    = B_VERTS + 64 * NV; // 3,350,000
static constexpr int B_F1    = B_F0 + 128 * NV;   // 9,750,000
static constexpr int B_F2    = B_F1 + 256 * NV;   // 22,550,000

template <int MODE>
__global__ __launch_bounds__(256) void gp_main_k(
    const float* __restrict__ verts,
    const float* __restrict__ f0, const float* __restrict__ f1,
    const float* __restrict__ f2, const float* __restrict__ f3,
    const int* __restrict__ params, float* __restrict__ out) {
  int j = blockIdx.x * 256 + threadIdx.x;
  if (j >= TOTAL) return;

  if (j < B_VERTS) {
    int n = j / 3;
    int col = j - 3 * n;
    out[n * 963 + col] = verts[j];
    return;
  }

  int n, outcol;
  float val = 0.0f;
  if (j < B_F0) {
    int t = j - B_VERTS; n = t >> 6; int c = t & 63;
    int off = get_off<MODE>(params, verts, n, 0, 0.25f, 56);
    if (off >= 0) val = f0[c * 3136 + off];
    outcol = 3 + c;
  } else if (j < B_F1) {
    int t = j - B_F0; n = t >> 7; int c = t & 127;
    int off = get_off<MODE>(params, verts, n, 1, 0.125f, 28);
    if (off >= 0) val = f1[c * 784 + off];
    outcol = 67 + c;
  } else if (j < B_F2) {
    int t = j - B_F1; n = t >> 8; int c = t & 255;
    int off = get_off<MODE>(params, verts, n, 2, 0.0625f, 14);
    if (off >= 0) val = f2[c * 196 + off];
    outcol = 195 + c;
  } else {
    int t = j - B_F2; n = t >> 9; int c = t & 511;
    int off = get_off<MODE>(params, verts, n, 3, 0.03125f, 7);
    if (off >= 0) val = f3[c * 49 + off];
    outcol = 451 + c;
  }
  out[n * 963 + outcol] = val;
}

extern "C" void kernel_launch(void* const* d_in, const int* in_sizes, int n_in,
                              void* d_out, int out_size, void* d_ws, size_t ws_size,
                              hipStream_t stream) {
  const float* f0    = (const float*)d_in[0];
  const float* f1    = (const float*)d_in[1];
  const float* f2    = (const float*)d_in[2];
  const float* f3    = (const float*)d_in[3];
  const float* verts = (const float*)d_in[4];
  float* out = (float*)d_out;

  const size_t PARAM_BYTES = (size_t)NV * 4 * sizeof(int);  // 800,000 (16B-aligned)
  const size_t FULL_BYTES  = PARAM_BYTES + (size_t)(TSUM + ZN) * sizeof(float);

  if (ws_size >= FULL_BYTES) {
    int*   params = (int*)d_ws;
    float* t0 = (float*)((char*)d_ws + PARAM_BYTES);
    float* t1 = t0 + T0;
    float* t2 = t1 + T1;
    float* t3 = t2 + T2;
    float* zeros = t3 + T3;
    prep_params_k<<<(NV + 255) / 256, 256, 0, stream>>>(verts, params);
    transpose_k<<<(TSUM + ZN + 255) / 256, 256, 0, stream>>>(f0, f1, f2, f3,
                                                             t0, t1, t2, t3, zeros);
    const int rowBlocks = (NV * 64 + 255) / 256;  // 12,500 (one wave per vertex)
    gp_row_k<<<rowBlocks, 256, 0, stream>>>(verts, t0, t1, t2, t3, zeros, params, out);
  } else if (ws_size >= PARAM_BYTES) {
    int* params = (int*)d_ws;
    prep_params_k<<<(NV + 255) / 256, 256, 0, stream>>>(verts, params);
    gp_main_k<1><<<(TOTAL + 255) / 256, 256, 0, stream>>>(verts, f0, f1, f2, f3, params, out);
  } else {
    gp_main_k<2><<<(TOTAL + 255) / 256, 256, 0, stream>>>(verts, f0, f1, f2, f3, nullptr, out);
  }
}